// Round 8
// baseline (143.296 us; speedup 1.0000x reference)
//
#include <hip/hip_runtime.h>

#define FEPS 1e-12f

typedef __attribute__((ext_vector_type(8))) short short8;   // 8 bf16 = 4 VGPR
typedef __attribute__((ext_vector_type(4))) float floatx4;  // MFMA C/D

constexpr int NB = 64, D = 256, T = 4096, K = 64, S = 8;
constexpr int TC = 64;           // pixels per chunk
constexpr int TBLK = T / S;      // 512 pixels per block
constexpr int NCH = TBLK / TC;   // 8 chunks

// f32 -> bf16 round-to-nearest-even
__device__ __forceinline__ unsigned short f2bf(float f) {
    unsigned u = __float_as_uint(f);
    return (unsigned short)((u + 0x7FFFu + ((u >> 16) & 1u)) >> 16);
}
__device__ __forceinline__ unsigned pk2(float a, float b) {
    return (unsigned)f2bf(a) | ((unsigned)f2bf(b) << 16);
}

// Workgroup barrier WITHOUT the implicit vmcnt(0) drain __syncthreads emits.
// lgkmcnt(0) orders our ds ops; register-destined global prefetch loads
// legally stay in flight across it.
__device__ __forceinline__ void barrier_nd() {
    __builtin_amdgcn_sched_barrier(0);
    asm volatile("s_waitcnt lgkmcnt(0)" ::: "memory");
    __builtin_amdgcn_s_barrier();
    __builtin_amdgcn_sched_barrier(0);
}

// Fused: L2-norm factor + logits MFMA-GEMM + softmax + aggregation MFMA-GEMM.
// One 512-thread (8-wave) block per (n, t-split). TC=64: every global load
// instruction covers 4 rows x 256B contiguous. LDS 75KB -> 2 blocks/CU = 16
// waves/CU; __launch_bounds__(512,2) = 4 waves/EU -> 128-VGPR cap (no spill).
// CHANNEL SPREAD: x rows are 16KB apart (channel residue = 64d mod 128 -> 2
// values) and n's 4MB stride contributes 0, so the only HBM-channel entropy
// is (ts, chunk). Blocks start phase-synced -> ~12% of channels active.
// Fix: per-block chunk-order rotation pc = (c + bid%8) & 7 -> all chunk
// phases (hence all channel residues) active at every instant.
__global__ __launch_bounds__(512, 2)
void nv_main(const float* __restrict__ x, const float* __restrict__ w,
             float* __restrict__ vout, float* __restrict__ suma)
{
    __shared__ __align__(16) unsigned char smem[76800];
    unsigned short* xs1 = (unsigned short*)smem;            // [t][d^swz] 32KB
    unsigned short* xs2 = (unsigned short*)(smem + 32768);  // [d][t^swz] 32KB
    unsigned short* bmm = (unsigned short*)(smem + 65536);  // [k][t^swz]  8KB
    float* sps = (float*)(smem + 73728);                    // [t][4] denom
    float* sqp = (float*)(smem + 74752);                    // [wv][64] sumsq
    float* fb  = (float*)smem;                              // epilogue [k][d]

    const int tid = threadIdx.x;
    const int wv = tid >> 6, ln = tid & 63;
    const int m = ln & 15, g = ln >> 4;     // MFMA/staging lane decomposition
    const int a = wv & 3, b = wv >> 2;      // GEMM1: k-band a, t-half b
    const int bid = blockIdx.x;
    const int n = (bid & 7) * 8 + ((bid >> 3) & 7);   // XCD-confined n octet
    const int ts = bid >> 6;                           // t-split 0..7
    const int coff = bid & 7;                          // chunk-order rotation

    const float* xn = x + (size_t)n * D * T;

    // Resident W A-frags for k-band a = [16a, 16a+16)
    short8 wf[8];
    {
        const float* wp = w + (16 * a + m) * D + 8 * g;
        #pragma unroll
        for (int ks = 0; ks < 8; ++ks) {
            float4 q0 = *(const float4*)(wp + 32 * ks);
            float4 q1 = *(const float4*)(wp + 32 * ks + 4);
            union { short8 v; unsigned u[4]; } t_;
            t_.u[0] = pk2(q0.x, q0.y); t_.u[1] = pk2(q0.z, q0.w);
            t_.u[2] = pk2(q1.x, q1.y); t_.u[3] = pk2(q1.z, q1.w);
            wf[ks] = t_.v;
        }
    }

    floatx4 acc[4][2];                       // GEMM2 acc [mt(k)][nt2(d)]
    floatx4 fzero = {0.f, 0.f, 0.f, 0.f};
    #pragma unroll
    for (int p = 0; p < 4; ++p) { acc[p][0] = fzero; acc[p][1] = fzero; }
    float sa[4] = {0.f, 0.f, 0.f, 0.f};      // sum_t a for k = 16a+4g+reg

    // ---- prologue: prefetch rotated chunk 0 (8 float4/thread; 4x256B/instr)
    float4 pv[8];
    {
        const int t0 = ts * TBLK + coff * TC;
        #pragma unroll
        for (int s = 0; s < 8; ++s)
            pv[s] = *(const float4*)(xn + (size_t)(32 * wv + 4 * s + g) * T
                                     + t0 + 4 * m);
    }

    for (int c = 0; c < NCH; ++c) {
        barrier_nd();                        // xs/bm free (prev chunk done)

        // ---- stage: pv (f32) -> bf16 into xs2 [d][t] and xs1 [t][d] (4x4
        //      lane transpose across g via shfl_xor 16/32), sumsq fused
        float4 sq4 = {0.f, 0.f, 0.f, 0.f};
        #pragma unroll
        for (int s = 0; s < 8; ++s) {
            const int d = 32 * wv + 4 * s + g;
            float4 v = pv[s];
            sq4.x = fmaf(v.x, v.x, sq4.x); sq4.y = fmaf(v.y, v.y, sq4.y);
            sq4.z = fmaf(v.z, v.z, sq4.z); sq4.w = fmaf(v.w, v.w, sq4.w);
            unsigned lo = pk2(v.x, v.y), hi = pk2(v.z, v.w);
            uint2 st2; st2.x = lo; st2.y = hi;          // 4 bf16 along t
            *(uint2*)(&xs2[d * TC + ((4 * m) ^ (8 * (d & 7)))]) = st2;
            // 4x4 bf16 transpose across lanes g (d rows <-> t cols)
            unsigned plo = __shfl_xor(lo, 16), phi = __shfl_xor(hi, 16);
            unsigned lo1, hi1;
            if ((g & 1) == 0) { lo1 = (lo & 0xFFFFu) | (plo << 16);
                                hi1 = (hi & 0xFFFFu) | (phi << 16); }
            else              { lo1 = (lo >> 16) | (plo & 0xFFFF0000u);
                                hi1 = (hi >> 16) | (phi & 0xFFFF0000u); }
            unsigned slo = __shfl_xor(lo1, 32), shi = __shfl_xor(hi1, 32);
            uint2 ot;
            if ((g & 2) == 0) { ot.x = lo1; ot.y = slo; }
            else              { ot.x = shi; ot.y = hi1; }
            const int tt = 4 * m + g;                   // t this lane owns
            const int db = 32 * wv + 4 * s;             // 4 d's, ascending
            *(uint2*)(&xs1[tt * D + (db ^ (8 * (tt & 31)))]) = ot;
        }

        // ---- prefetch rotated chunk c+1 NOW (in flight across barrier and
        //      all compute phases below)
        if (c + 1 < NCH) {
            const int tn = ts * TBLK + (((c + 1 + coff) & 7)) * TC;
            #pragma unroll
            for (int s = 0; s < 8; ++s)
                pv[s] = *(const float4*)(xn + (size_t)(32 * wv + 4 * s + g) * T
                                         + tn + 4 * m);
        }

        // per-t sumsq partial (this wave's 32 d's): reduce over g
        #pragma unroll
        for (int msk = 16; msk <= 32; msk <<= 1) {
            sq4.x += __shfl_xor(sq4.x, msk); sq4.y += __shfl_xor(sq4.y, msk);
            sq4.z += __shfl_xor(sq4.z, msk); sq4.w += __shfl_xor(sq4.w, msk);
        }
        if (g == 0) *(float4*)(&sqp[wv * 64 + 4 * m]) = sq4;
        barrier_nd();                        // publish xs1/xs2/sqp

        // ---- r[t] = 1/max(||x[:,t]||,eps) for this wave's 2 t-columns
        float r4[2];
        #pragma unroll
        for (int nt = 0; nt < 2; ++nt) {
            const int t = 32 * b + 16 * nt + m;
            float ss = 0.f;
            #pragma unroll
            for (int j = 0; j < 8; ++j) ss += sqp[j * 64 + t];
            r4[nt] = 1.f / fmaxf(sqrtf(ss), FEPS);
        }

        // ---- GEMM1: z[16 k][32 t] = W * x  (contract d=256)
        floatx4 z[2];
        z[0] = fzero; z[1] = fzero;
        __builtin_amdgcn_s_setprio(1);
        #pragma unroll
        for (int ks = 0; ks < 8; ++ks) {
            #pragma unroll
            for (int nt = 0; nt < 2; ++nt) {
                const int t = 32 * b + 16 * nt + m;
                short8 bfr = *(const short8*)(
                    &xs1[t * D + ((32 * ks + 8 * g) ^ (8 * (t & 31)))]);
                z[nt] = __builtin_amdgcn_mfma_f32_16x16x32_bf16(
                    wf[ks], bfr, z[nt], 0, 0, 0);
            }
        }
        __builtin_amdgcn_s_setprio(0);

        // ---- softmax over k (no max-sub: |logit| <= ||w_row|| ~ 1)
        float e[2][4], psum[2];
        #pragma unroll
        for (int nt = 0; nt < 2; ++nt) {
            const float r = r4[nt];
            float p = 0.f;
            #pragma unroll
            for (int reg = 0; reg < 4; ++reg) {
                float ex = __expf(z[nt][reg] * r);
                e[nt][reg] = ex; p += ex;
            }
            psum[nt] = p;
        }
        #pragma unroll
        for (int nt = 0; nt < 2; ++nt) {     // reduce over g: wave's 16 k's
            psum[nt] += __shfl_xor(psum[nt], 16);
            psum[nt] += __shfl_xor(psum[nt], 32);
        }
        if (g == 0) {
            #pragma unroll
            for (int nt = 0; nt < 2; ++nt)
                sps[(32 * b + 16 * nt + m) * 4 + a] = psum[nt];
        }
        barrier_nd();                        // publish sps
        #pragma unroll
        for (int nt = 0; nt < 2; ++nt) {
            const int t = 32 * b + 16 * nt + m;
            float4 sv = *(const float4*)(&sps[t * 4]);
            const float inv = 1.f / (sv.x + sv.y + sv.z + sv.w);
            const float br = inv * r4[nt];
            #pragma unroll
            for (int reg = 0; reg < 4; ++reg) {
                const int k = 16 * a + 4 * g + reg;
                bmm[k * TC + (t ^ (8 * (k & 7)))] = f2bf(e[nt][reg] * br);
                sa[reg] += e[nt][reg] * inv;
            }
        }
        barrier_nd();                        // publish bm

        // ---- GEMM2: acc[k][d] += b[k][t] * x[d][t]  (contract t=64)
        #pragma unroll
        for (int kt = 0; kt < 2; ++kt) {
            short8 af[4], bf[2];
            #pragma unroll
            for (int mt = 0; mt < 4; ++mt) {
                const int k = 16 * mt + m;
                af[mt] = *(const short8*)(
                    &bmm[k * TC + ((32 * kt + 8 * g) ^ (8 * (k & 7)))]);
            }
            #pragma unroll
            for (int nt2 = 0; nt2 < 2; ++nt2) {
                const int d = 32 * wv + 16 * nt2 + m;
                bf[nt2] = *(const short8*)(
                    &xs2[d * TC + ((32 * kt + 8 * g) ^ (8 * (d & 7)))]);
            }
            __builtin_amdgcn_s_setprio(1);
            #pragma unroll
            for (int mt = 0; mt < 4; ++mt)
                #pragma unroll
                for (int nt2 = 0; nt2 < 2; ++nt2)
                    acc[mt][nt2] = __builtin_amdgcn_mfma_f32_16x16x32_bf16(
                        af[mt], bf[nt2], acc[mt][nt2], 0, 0, 0);
            __builtin_amdgcn_s_setprio(0);
        }
    }

    // ---- epilogue: reassemble block partial in LDS, flush with 256B bursts
    barrier_nd();                            // xs dead -> reuse as fb [k][d]
    #pragma unroll
    for (int mt = 0; mt < 4; ++mt)
        #pragma unroll
        for (int nt2 = 0; nt2 < 2; ++nt2)
            #pragma unroll
            for (int reg = 0; reg < 4; ++reg)
                fb[(16 * mt + 4 * g + reg) * D + 32 * wv + 16 * nt2 + m] =
                    acc[mt][nt2][reg];
    barrier_nd();
    {
        float* vs = vout + (size_t)n * K * D;
        #pragma unroll
        for (int j = 0; j < 32; ++j) {
            const int off = wv * 2048 + j * 64 + ln;  // 64 lanes x 4B = 256B
            atomicAdd(&vs[off], fb[off]);
        }
    }
    #pragma unroll
    for (int reg = 0; reg < 4; ++reg) {
        float v = sa[reg];
        v += __shfl_xor(v, 1); v += __shfl_xor(v, 2);
        v += __shfl_xor(v, 4); v += __shfl_xor(v, 8);
        if (m == 0) atomicAdd(&suma[n * K + 16 * a + 4 * g + reg], v);
    }
}

// per (n,k): subtract suma*centroid, intra-normalize over d, accum final sumsq
__global__ void nv_finish_row(const float* __restrict__ cent,
                              const float* __restrict__ suma,
                              float* __restrict__ out,
                              float* __restrict__ nsum)
{
    const int bid = blockIdx.x;          // n*64 + k
    const int nn = bid >> 6, k = bid & 63;
    const int d = threadIdx.x;
    float v = out[(size_t)bid * D + d] - suma[bid] * cent[k * D + d];
    float sv = v * v;
    #pragma unroll
    for (int msk = 1; msk < 64; msk <<= 1) sv += __shfl_xor(sv, msk);
    __shared__ float red[4];
    __shared__ float stot;
    if ((d & 63) == 0) red[d >> 6] = sv;
    __syncthreads();
    if (d == 0) stot = red[0] + red[1] + red[2] + red[3];
    __syncthreads();
    const float s = stot;
    const float inv = 1.f / fmaxf(sqrtf(s), FEPS);
    out[(size_t)bid * D + d] = v * inv;
    if (d == 0) atomicAdd(&nsum[nn], s * inv * inv);
}

// final L2 over the flattened (K*D) per n
__global__ void nv_final(float* __restrict__ out, const float* __restrict__ nsum) {
    const int idx = blockIdx.x * 256 + threadIdx.x;
    const int n = idx >> 14;             // /16384
    out[idx] *= 1.f / fmaxf(sqrtf(nsum[n]), FEPS);
}

extern "C" void kernel_launch(void* const* d_in, const int* in_sizes, int n_in,
                              void* d_out, int out_size, void* d_ws, size_t ws_size,
                              hipStream_t stream)
{
    const float* x    = (const float*)d_in[0];
    const float* w    = (const float*)d_in[1];
    const float* cent = (const float*)d_in[2];
    float* out = (float*)d_out;

    // ws layout: suma[NB*K] | nsum[NB]
    float* suma = (float*)d_ws;
    float* nsum = suma + NB * K;

    hipMemsetAsync(d_ws, 0, (size_t)(NB * K + NB) * sizeof(float), stream);
    hipMemsetAsync(d_out, 0, (size_t)NB * K * D * sizeof(float), stream);

    nv_main<<<S * NB, 512, 0, stream>>>(x, w, out, suma);
    nv_finish_row<<<NB * K, 256, 0, stream>>>(cent, suma, out, nsum);
    nv_final<<<(NB * K * D) / 256, 256, 0, stream>>>(out, nsum);
}

// Round 10
// 123.375 us; speedup vs baseline: 1.1615x; 1.1615x over previous
//
#include <hip/hip_runtime.h>

#define FEPS 1e-12f

typedef __attribute__((ext_vector_type(8))) short short8;   // 8 bf16 = 4 VGPR
typedef __attribute__((ext_vector_type(4))) short bf16x4;   // 4 bf16 = 2 VGPR
typedef __attribute__((ext_vector_type(4))) float floatx4;  // MFMA C/D

constexpr int NB = 64, D = 256, T = 4096, K = 64, S = 8;
constexpr int TC = 64;           // pixels per chunk
constexpr int TBLK = T / S;      // 512 pixels per block
constexpr int NCH = TBLK / TC;   // 8 chunks

// f32 -> bf16 round-to-nearest-even
__device__ __forceinline__ unsigned short f2bf(float f) {
    unsigned u = __float_as_uint(f);
    return (unsigned short)((u + 0x7FFFu + ((u >> 16) & 1u)) >> 16);
}
__device__ __forceinline__ unsigned pk2(float a, float b) {
    return (unsigned)f2bf(a) | ((unsigned)f2bf(b) << 16);
}

// Workgroup barrier WITHOUT the implicit vmcnt(0) drain __syncthreads emits.
// lgkmcnt(0) orders our ds ops; register-destined global prefetch loads
// legally stay in flight across it.
__device__ __forceinline__ void barrier_nd() {
    __builtin_amdgcn_sched_barrier(0);
    asm volatile("s_waitcnt lgkmcnt(0)" ::: "memory");
    __builtin_amdgcn_s_barrier();
    __builtin_amdgcn_sched_barrier(0);
}

// Fused: L2-norm factor + logits MFMA-GEMM + softmax + aggregation MFMA-GEMM.
// x tile lives ONCE in LDS in the tr-read subtile layout
//   byte(d,t) = (d>>5)*4096 + (t>>4)*1024 + (d&31)*32 + (t&15)*2   [32x16 bf16]
// GEMM1 B-frags come from ds_read_b64_tr_b16 (per-lane base, stride-32B HW
// gather) -> no in-register 4x4 shuffle transpose, no second LDS copy.
// Freed 32KB double-buffers the x tile -> 3 barriers/chunk (was 4).
// TC=64: every global load = 4 rows x 256B contiguous. LDS 75KB -> 2
// blocks/CU = 16 waves/CU; __launch_bounds__(512,2) -> 128-VGPR cap.
__global__ __launch_bounds__(512, 2)
void nv_main(const float* __restrict__ x, const float* __restrict__ w,
             float* __restrict__ vout, float* __restrict__ suma)
{
    __shared__ __align__(16) unsigned char smem[76800];
    // 0      .. 65536 : xt[2][32768]  x tiles (subtiled bf16, double-buffered)
    // 65536  .. 73728 : bm [k][64 t ^ 8(k&7)] bf16 (8 KB)
    // 73728  .. 74752 : sps[64 t][4] f32 softmax denom partials
    // 74752  .. 76800 : sqp[8 wv][64 t] f32 sumsq partials
    // epilogue: fb = smem[0..65536) reused as f32 [k][d]
    unsigned short* bmm = (unsigned short*)(smem + 65536);
    float* sps = (float*)(smem + 73728);
    float* sqp = (float*)(smem + 74752);
    float* fb  = (float*)smem;

    const int tid = threadIdx.x;
    const int wv = tid >> 6, ln = tid & 63;
    const int m = ln & 15, g = ln >> 4;     // MFMA/staging lane decomposition
    const int a = wv & 3, b = wv >> 2;      // GEMM1: k-band a, t-half b
    const int bid = blockIdx.x;
    const int n = (bid & 7) * 8 + ((bid >> 3) & 7);   // XCD-confined n octet
    const int ts = bid >> 6;                           // t-split 0..7

    const float* xn = x + (size_t)n * D * T;

    // Resident W A-frags for k-band a = [16a, 16a+16)
    short8 wf[8];
    {
        const float* wp = w + (16 * a + m) * D + 8 * g;
        #pragma unroll
        for (int ks = 0; ks < 8; ++ks) {
            float4 q0 = *(const float4*)(wp + 32 * ks);
            float4 q1 = *(const float4*)(wp + 32 * ks + 4);
            union { short8 v; unsigned u[4]; } t_;
            t_.u[0] = pk2(q0.x, q0.y); t_.u[1] = pk2(q0.z, q0.w);
            t_.u[2] = pk2(q1.x, q1.y); t_.u[3] = pk2(q1.z, q1.w);
            wf[ks] = t_.v;
        }
    }

    floatx4 acc[4][2];                       // GEMM2 acc [mt(k)][nt2(d)]
    floatx4 fzero = {0.f, 0.f, 0.f, 0.f};
    #pragma unroll
    for (int p = 0; p < 4; ++p) { acc[p][0] = fzero; acc[p][1] = fzero; }
    float sa[4] = {0.f, 0.f, 0.f, 0.f};      // sum_t a for k = 16a+4g+reg

    float4 pv[8];
    auto do_issue = [&](int cc) {            // 8 float4/thread; 4x256B/instr
        const int tn = ts * TBLK + cc * TC;
        #pragma unroll
        for (int s = 0; s < 8; ++s)
            pv[s] = *(const float4*)(xn + (size_t)(32 * wv + 4 * s + g) * T
                                     + tn + 4 * m);
    };
    // stage pv -> bf16 subtiled xt[bufsel] (1 ds_write_b64/row-quad) + sumsq
    auto do_stage = [&](int bufsel) {
        float4 sq4 = {0.f, 0.f, 0.f, 0.f};
        #pragma unroll
        for (int s = 0; s < 8; ++s) {
            float4 v = pv[s];
            sq4.x = fmaf(v.x, v.x, sq4.x); sq4.y = fmaf(v.y, v.y, sq4.y);
            sq4.z = fmaf(v.z, v.z, sq4.z); sq4.w = fmaf(v.w, v.w, sq4.w);
            uint2 st2; st2.x = pk2(v.x, v.y); st2.y = pk2(v.z, v.w);
            const int dd = 4 * s + g;        // d & 31 (d = 32wv + dd)
            *(uint2*)(smem + bufsel * 32768 + wv * 4096 + (m >> 2) * 1024
                      + dd * 32 + (m & 3) * 8) = st2;
        }
        #pragma unroll
        for (int msk = 16; msk <= 32; msk <<= 1) {
            sq4.x += __shfl_xor(sq4.x, msk); sq4.y += __shfl_xor(sq4.y, msk);
            sq4.z += __shfl_xor(sq4.z, msk); sq4.w += __shfl_xor(sq4.w, msk);
        }
        if (g == 0) *(float4*)(&sqp[wv * 64 + 4 * m]) = sq4;
    };

    // ---- prologue: load + stage chunk 0, issue chunk 1
    do_issue(0);
    do_stage(0);
    do_issue(1);

    for (int c = 0; c < NCH; ++c) {
        const int cur = c & 1;
        barrier_nd();                        // B_A: publish xt[cur] + sqp

        // ---- r[t] = 1/max(||x[:,t]||,eps) for this wave's 2 t-columns
        float r4[2];
        #pragma unroll
        for (int nt = 0; nt < 2; ++nt) {
            const int t = 32 * b + 16 * nt + m;
            float ss = 0.f;
            #pragma unroll
            for (int j = 0; j < 8; ++j) ss += sqp[j * 64 + t];
            r4[nt] = 1.f / fmaxf(sqrtf(ss), FEPS);
        }
        asm volatile("s_waitcnt lgkmcnt(0)" ::: "memory");
        __builtin_amdgcn_sched_barrier(0);

        // ---- GEMM1: z[16 k][32 t] = W * x, B-frags via HW transpose-read.
        //      Lane (m,g) frag (ks,nt): x[d=32ks+8g+j][t=32b+16nt+m], j=0..7
        //      = 2 x tr_b64 gathers (stride 32 B), 2-deep lgkmcnt pipeline.
        floatx4 z[2];
        z[0] = fzero; z[1] = fzero;
        const int trb = cur * 32768 + 2048 * b + 256 * g + 2 * m;
        bf16x4 hb[2][2][2];                  // [pipe][nt][half]
        {
            asm volatile("ds_read_b64_tr_b16 %0, %2 offset:0\n\t"
                         "ds_read_b64_tr_b16 %1, %2 offset:128"
                         : "=&v"(hb[0][0][0]), "=&v"(hb[0][0][1])
                         : "v"(trb));
            asm volatile("ds_read_b64_tr_b16 %0, %2 offset:0\n\t"
                         "ds_read_b64_tr_b16 %1, %2 offset:128"
                         : "=&v"(hb[0][1][0]), "=&v"(hb[0][1][1])
                         : "v"(trb + 1024));
        }
        #pragma unroll
        for (int ks = 0; ks < 8; ++ks) {
            const int pc = ks & 1;
            if (ks < 7) {
                const int an = trb + (ks + 1) * 4096;
                asm volatile("ds_read_b64_tr_b16 %0, %2 offset:0\n\t"
                             "ds_read_b64_tr_b16 %1, %2 offset:128"
                             : "=&v"(hb[pc ^ 1][0][0]), "=&v"(hb[pc ^ 1][0][1])
                             : "v"(an));
                asm volatile("ds_read_b64_tr_b16 %0, %2 offset:0\n\t"
                             "ds_read_b64_tr_b16 %1, %2 offset:128"
                             : "=&v"(hb[pc ^ 1][1][0]), "=&v"(hb[pc ^ 1][1][1])
                             : "v"(an + 1024));
                asm volatile("s_waitcnt lgkmcnt(4)" ::: "memory");
            } else {
                asm volatile("s_waitcnt lgkmcnt(0)" ::: "memory");
            }
            __builtin_amdgcn_sched_barrier(0);
            #pragma unroll
            for (int nt = 0; nt < 2; ++nt) {
                short8 bfr = __builtin_shufflevector(
                    hb[pc][nt][0], hb[pc][nt][1], 0, 1, 2, 3, 4, 5, 6, 7);
                z[nt] = __builtin_amdgcn_mfma_f32_16x16x32_bf16(
                    wf[ks], bfr, z[nt], 0, 0, 0);
            }
        }

        // ---- softmax over k (no max-sub: |logit| <= ||w_row|| ~ 1)
        float e[2][4], psum[2];
        #pragma unroll
        for (int nt = 0; nt < 2; ++nt) {
            const float r = r4[nt];
            float p = 0.f;
            #pragma unroll
            for (int reg = 0; reg < 4; ++reg) {
                float ex = __expf(z[nt][reg] * r);
                e[nt][reg] = ex; p += ex;
            }
            psum[nt] = p;
        }
        #pragma unroll
        for (int nt = 0; nt < 2; ++nt) {     // reduce over g: wave's 16 k's
            psum[nt] += __shfl_xor(psum[nt], 16);
            psum[nt] += __shfl_xor(psum[nt], 32);
        }
        if (g == 0) {
            #pragma unroll
            for (int nt = 0; nt < 2; ++nt)
                sps[(32 * b + 16 * nt + m) * 4 + a] = psum[nt];
        }
        barrier_nd();                        // B_B: publish sps
        #pragma unroll
        for (int nt = 0; nt < 2; ++nt) {
            const int t = 32 * b + 16 * nt + m;
            float4 sv = *(const float4*)(&sps[t * 4]);
            const float inv = 1.f / (sv.x + sv.y + sv.z + sv.w);
            const float br = inv * r4[nt];
            #pragma unroll
            for (int reg = 0; reg < 4; ++reg) {
                const int k = 16 * a + 4 * g + reg;
                bmm[k * TC + (t ^ (8 * (k & 7)))] = f2bf(e[nt][reg] * br);
                sa[reg] += e[nt][reg] * inv;
            }
        }
        barrier_nd();                        // B_C: publish bm

        // ---- GEMM2: acc[k][d] += b[k][t] * x[d][t]  (contract t=64)
        #pragma unroll
        for (int kt = 0; kt < 2; ++kt) {
            short8 af[4], bf[2];
            #pragma unroll
            for (int mt = 0; mt < 4; ++mt) {
                const int k = 16 * mt + m;
                af[mt] = *(const short8*)(
                    &bmm[k * TC + ((32 * kt + 8 * g) ^ (8 * (k & 7)))]);
            }
            #pragma unroll
            for (int nt2 = 0; nt2 < 2; ++nt2)
                bf[nt2] = *(const short8*)(smem + cur * 32768 + wv * 4096
                           + (2 * kt + (g >> 1)) * 1024
                           + (16 * nt2 + m) * 32 + (g & 1) * 16);
            #pragma unroll
            for (int mt = 0; mt < 4; ++mt)
                #pragma unroll
                for (int nt2 = 0; nt2 < 2; ++nt2)
                    acc[mt][nt2] = __builtin_amdgcn_mfma_f32_16x16x32_bf16(
                        af[mt], bf[nt2], acc[mt][nt2], 0, 0, 0);
        }

        // ---- stage chunk c+1 into other buffer; issue chunk c+2 loads
        if (c + 1 < NCH) do_stage(cur ^ 1);
        if (c + 2 < NCH) do_issue(c + 2);
    }

    // ---- epilogue: reassemble block partial in LDS, flush with 256B bursts
    barrier_nd();                            // xt dead -> reuse as fb [k][d]
    #pragma unroll
    for (int mt = 0; mt < 4; ++mt)
        #pragma unroll
        for (int nt2 = 0; nt2 < 2; ++nt2)
            #pragma unroll
            for (int reg = 0; reg < 4; ++reg)
                fb[(16 * mt + 4 * g + reg) * D + 32 * wv + 16 * nt2 + m] =
                    acc[mt][nt2][reg];
    barrier_nd();
    {
        float* vs = vout + (size_t)n * K * D;
        #pragma unroll
        for (int j = 0; j < 32; ++j) {
            const int off = wv * 2048 + j * 64 + ln;  // 64 lanes x 4B = 256B
            atomicAdd(&vs[off], fb[off]);
        }
    }
    #pragma unroll
    for (int reg = 0; reg < 4; ++reg) {
        float v = sa[reg];
        v += __shfl_xor(v, 1); v += __shfl_xor(v, 2);
        v += __shfl_xor(v, 4); v += __shfl_xor(v, 8);
        if (m == 0) atomicAdd(&suma[n * K + 16 * a + 4 * g + reg], v);
    }
}

// per (n,k): subtract suma*centroid, intra-normalize over d, accum final sumsq
__global__ void nv_finish_row(const float* __restrict__ cent,
                              const float* __restrict__ suma,
                              float* __restrict__ out,
                              float* __restrict__ nsum)
{
    const int bid = blockIdx.x;          // n*64 + k
    const int nn = bid >> 6, k = bid & 63;
    const int d = threadIdx.x;
    float v = out[(size_t)bid * D + d] - suma[bid] * cent[k * D + d];
    float sv = v * v;
    #pragma unroll
    for (int msk = 1; msk < 64; msk <<= 1) sv += __shfl_xor(sv, msk);
    __shared__ float red[4];
    __shared__ float stot;
    if ((d & 63) == 0) red[d >> 6] = sv;
    __syncthreads();
    if (d == 0) stot = red[0] + red[1] + red[2] + red[3];
    __syncthreads();
    const float s = stot;
    const float inv = 1.f / fmaxf(sqrtf(s), FEPS);
    out[(size_t)bid * D + d] = v * inv;
    if (d == 0) atomicAdd(&nsum[nn], s * inv * inv);
}

// final L2 over the flattened (K*D) per n
__global__ void nv_final(float* __restrict__ out, const float* __restrict__ nsum) {
    const int idx = blockIdx.x * 256 + threadIdx.x;
    const int n = idx >> 14;             // /16384
    out[idx] *= 1.f / fmaxf(sqrtf(nsum[n]), FEPS);
}

extern "C" void kernel_launch(void* const* d_in, const int* in_sizes, int n_in,
                              void* d_out, int out_size, void* d_ws, size_t ws_size,
                              hipStream_t stream)
{
    const float* x    = (const float*)d_in[0];
    const float* w    = (const float*)d_in[1];
    const float* cent = (const float*)d_in[2];
    float* out = (float*)d_out;

    // ws layout: suma[NB*K] | nsum[NB]
    float* suma = (float*)d_ws;
    float* nsum = suma + NB * K;

    (void)hipMemsetAsync(d_ws, 0, (size_t)(NB * K + NB) * sizeof(float), stream);
    (void)hipMemsetAsync(d_out, 0, (size_t)NB * K * D * sizeof(float), stream);

    nv_main<<<S * NB, 512, 0, stream>>>(x, w, out, suma);
    nv_finish_row<<<NB * K, 256, 0, stream>>>(cent, suma, out, nsum);
    nv_final<<<(NB * K * D) / 256, 256, 0, stream>>>(out, nsum);
}